// Round 4
// baseline (292.528 us; speedup 1.0000x reference)
//
#include <hip/hip_runtime.h>
#include <math.h>

// CognitiveRouter: module routing (4) + grouped expert routing (16), combined
// hierarchical probs, top-4 + renorm.  T=32768, D=1536, fp32 in/out.
//
// R9 (R8 post-mortem: router ~56us. LDS port is CU-shared and ds_read_b128
// costs ~12cyc: 8 waves x 48 j-steps x 20 weight reads = 92k cyc = 38us of
// port time > 32us HBM floor. Each b128 fed only 8 FMAs (2 rows).)
// Change vs R8: 4 rows per lane in ONE pass (rA, rA+4, rA+8, rA+12), so
// every weight ds_read_b128 feeds 16 FMAs. Per-CU LDS port: 46k cyc =
// 19us < 32us HBM -> HBM becomes the pole. VALU 12.8us. ~180 VGPR < 256
// cap (512-thr block at 1 block/CU implies <=256 VGPR/wave, no spill).
// Keep from R8 (verified): weights LDS-resident once (122,880 B), wl[j][e][64]
// layout (16 distinct 16B slots x 4-way broadcast = 2-way bank dup, free);
// hs global->VGPR with named-reg j+=2 prefetch; __shfl_xor(1,2,4,8)
// reduction over 16 q-lanes; R6 epilogue math; grid 256 = 1 block/CU.

#define DD 1536
#define NM 4
#define NE 16
#define NW 20          // 16 expert rows + 4 module rows
#define RPB 128        // rows per block
#define NTHR 512
#define NJ 24          // DD / 64 column windows
#define WLDS_F (NJ * NW * 64)   // 30720 floats = 122880 B

typedef float v4f __attribute__((ext_vector_type(4)));

__global__ __launch_bounds__(NTHR)
void router_kernel(const float* __restrict__ hs,
                   const float* __restrict__ Wm,
                   const float* __restrict__ We,
                   float* __restrict__ out,
                   int T)
{
    __shared__ __align__(16) float wl[WLDS_F];   // weights only, read-only after stage
    const int tid  = threadIdx.x;
    const int wv   = tid >> 6;
    const int lane = tid & 63;
    const int q    = lane & 15;       // col-group lane within 64-col window
    const int g    = lane >> 4;       // row sub-group 0..3
    const int rowBlock = blockIdx.x * RPB;

    // ---- stage ALL weights to LDS once: wl[j][e][qcol], off=j*1280+e*64+qcol
    // 30720 floats = 512 threads x 15 v4, coalesced, distinct, exact cover.
#pragma unroll
    for (int i = 0; i < 15; i++) {
        const int off  = tid * 4 + i * 2048;
        const int j    = off / 1280;
        const int rem  = off - j * 1280;
        const int e    = rem >> 6;
        const int qcol = rem & 63;
        const int col  = j * 64 + qcol;
        v4f w = (e < NE) ? *(const v4f*)(We + (size_t)e * DD + col)
                         : *(const v4f*)(Wm + (size_t)(e - NE) * DD + col);
        *(v4f*)&wl[off] = w;
    }
    __syncthreads();

    // ---- 4 rows per lane, one pass: rA, rA+4, rA+8, rA+12 ----
    const int rA = rowBlock + wv * 16 + g;
    const float* hsA = hs + (size_t)rA * DD + q * 4;
    const float* hsB = hsA + (size_t)4 * DD;
    const float* hsC = hsA + (size_t)8 * DD;
    const float* hsD = hsA + (size_t)12 * DD;

    float accA[NW], accB[NW], accC[NW], accD[NW];
#pragma unroll
    for (int e = 0; e < NW; e++) { accA[e] = 0.f; accB[e] = 0.f; accC[e] = 0.f; accD[e] = 0.f; }

    // named-reg prefetch, two j-windows in flight
    v4f a0 = *(const v4f*)(hsA);
    v4f b0 = *(const v4f*)(hsB);
    v4f c0 = *(const v4f*)(hsC);
    v4f d0 = *(const v4f*)(hsD);
    v4f a1 = *(const v4f*)(hsA + 64);
    v4f b1 = *(const v4f*)(hsB + 64);
    v4f c1 = *(const v4f*)(hsC + 64);
    v4f d1 = *(const v4f*)(hsD + 64);

#pragma unroll 1
    for (int j = 0; j < NJ; j += 2) {
        v4f a2, b2, c2, d2, a3, b3, c3, d3;
        if (j + 2 < NJ) {
            a2 = *(const v4f*)(hsA + (size_t)(j + 2) * 64);
            b2 = *(const v4f*)(hsB + (size_t)(j + 2) * 64);
            c2 = *(const v4f*)(hsC + (size_t)(j + 2) * 64);
            d2 = *(const v4f*)(hsD + (size_t)(j + 2) * 64);
            a3 = *(const v4f*)(hsA + (size_t)(j + 3) * 64);
            b3 = *(const v4f*)(hsB + (size_t)(j + 3) * 64);
            c3 = *(const v4f*)(hsC + (size_t)(j + 3) * 64);
            d3 = *(const v4f*)(hsD + (size_t)(j + 3) * 64);
        }
        // step j: weights wl[j][e][q*4..+3], imm offsets e*256B; 16 FMA/read
        {
            const float* wb = &wl[j * 1280 + q * 4];
#pragma unroll
            for (int e = 0; e < NW; e++) {
                v4f w = *(const v4f*)(wb + e * 64);
                accA[e] = fmaf(a0.x, w.x, accA[e]); accA[e] = fmaf(a0.y, w.y, accA[e]);
                accA[e] = fmaf(a0.z, w.z, accA[e]); accA[e] = fmaf(a0.w, w.w, accA[e]);
                accB[e] = fmaf(b0.x, w.x, accB[e]); accB[e] = fmaf(b0.y, w.y, accB[e]);
                accB[e] = fmaf(b0.z, w.z, accB[e]); accB[e] = fmaf(b0.w, w.w, accB[e]);
                accC[e] = fmaf(c0.x, w.x, accC[e]); accC[e] = fmaf(c0.y, w.y, accC[e]);
                accC[e] = fmaf(c0.z, w.z, accC[e]); accC[e] = fmaf(c0.w, w.w, accC[e]);
                accD[e] = fmaf(d0.x, w.x, accD[e]); accD[e] = fmaf(d0.y, w.y, accD[e]);
                accD[e] = fmaf(d0.z, w.z, accD[e]); accD[e] = fmaf(d0.w, w.w, accD[e]);
            }
        }
        // step j+1
        {
            const float* wb = &wl[(j + 1) * 1280 + q * 4];
#pragma unroll
            for (int e = 0; e < NW; e++) {
                v4f w = *(const v4f*)(wb + e * 64);
                accA[e] = fmaf(a1.x, w.x, accA[e]); accA[e] = fmaf(a1.y, w.y, accA[e]);
                accA[e] = fmaf(a1.z, w.z, accA[e]); accA[e] = fmaf(a1.w, w.w, accA[e]);
                accB[e] = fmaf(b1.x, w.x, accB[e]); accB[e] = fmaf(b1.y, w.y, accB[e]);
                accB[e] = fmaf(b1.z, w.z, accB[e]); accB[e] = fmaf(b1.w, w.w, accB[e]);
                accC[e] = fmaf(c1.x, w.x, accC[e]); accC[e] = fmaf(c1.y, w.y, accC[e]);
                accC[e] = fmaf(c1.z, w.z, accC[e]); accC[e] = fmaf(c1.w, w.w, accC[e]);
                accD[e] = fmaf(d1.x, w.x, accD[e]); accD[e] = fmaf(d1.y, w.y, accD[e]);
                accD[e] = fmaf(d1.z, w.z, accD[e]); accD[e] = fmaf(d1.w, w.w, accD[e]);
            }
        }
        a0 = a2; b0 = b2; c0 = c2; d0 = d2;
        a1 = a3; b1 = b3; c1 = c3; d1 = d3;
    }

    // ---- in-register split-col reduction over the 16 q-lanes ----
#pragma unroll
    for (int e = 0; e < NW; e++) {
        accA[e] += __shfl_xor(accA[e], 1); accA[e] += __shfl_xor(accA[e], 2);
        accA[e] += __shfl_xor(accA[e], 4); accA[e] += __shfl_xor(accA[e], 8);
        accB[e] += __shfl_xor(accB[e], 1); accB[e] += __shfl_xor(accB[e], 2);
        accB[e] += __shfl_xor(accB[e], 4); accB[e] += __shfl_xor(accB[e], 8);
        accC[e] += __shfl_xor(accC[e], 1); accC[e] += __shfl_xor(accC[e], 2);
        accC[e] += __shfl_xor(accC[e], 4); accC[e] += __shfl_xor(accC[e], 8);
        accD[e] += __shfl_xor(accD[e], 1); accD[e] += __shfl_xor(accD[e], 2);
        accD[e] += __shfl_xor(accD[e], 4); accD[e] += __shfl_xor(accD[e], 8);
    }

    // ---- epilogue (verified R6 math): q==0..3 -> rows rA+4q ----
    if (q < 4) {
        float logit[NW];
#pragma unroll
        for (int e = 0; e < NW; e++)
            logit[e] = (q == 0) ? accA[e] : (q == 1) ? accB[e]
                     : (q == 2) ? accC[e] : accD[e];
        const int row = rA + q * 4;

        // module softmax over logit[16..19]
        float mmax = logit[16];
#pragma unroll
        for (int m = 1; m < NM; m++) mmax = fmaxf(mmax, logit[16 + m]);
        float mexp[NM], msum = 0.f;
#pragma unroll
        for (int m = 0; m < NM; m++) { mexp[m] = expf(logit[16 + m] - mmax); msum += mexp[m]; }

        // per-module expert softmax, combined probs
        float comb[NE];
#pragma unroll
        for (int m = 0; m < NM; m++) {
            float mprob = mexp[m] / msum;
            float emax = logit[m * 4];
#pragma unroll
            for (int jj = 1; jj < 4; jj++) emax = fmaxf(emax, logit[m * 4 + jj]);
            float ee[4], esum = 0.f;
#pragma unroll
            for (int jj = 0; jj < 4; jj++) { ee[jj] = expf(logit[m * 4 + jj] - emax); esum += ee[jj]; }
            float scale = mprob / esum;
#pragma unroll
            for (int jj = 0; jj < 4; jj++) comb[m * 4 + jj] = ee[jj] * scale;
        }

        float4* cw = (float4*)(out + (size_t)row * 16);
        cw[0] = make_float4(comb[0],  comb[1],  comb[2],  comb[3]);
        cw[1] = make_float4(comb[4],  comb[5],  comb[6],  comb[7]);
        cw[2] = make_float4(comb[8],  comb[9],  comb[10], comb[11]);
        cw[3] = make_float4(comb[12], comb[13], comb[14], comb[15]);

        // top-4, descending, strict > so lowest index wins ties (lax.top_k)
        float tv[4]; int ti[4];
        unsigned mask = 0;
#pragma unroll
        for (int k = 0; k < 4; k++) {
            float best = -1.f; int bi = 0;
#pragma unroll
            for (int i = 0; i < NE; i++) {
                bool avail = !((mask >> i) & 1u);
                if (avail && comb[i] > best) { best = comb[i]; bi = i; }
            }
            tv[k] = best; ti[k] = bi; mask |= 1u << bi;
        }
        float s = tv[0] + tv[1] + tv[2] + tv[3] + 1e-8f;

        const size_t wOff = (size_t)T * 16;          // top_k_weights region
        const size_t iOff = (size_t)T * 20;          // top_k_indices region
        float4* ww = (float4*)(out + wOff + (size_t)row * 4);
        *ww = make_float4(tv[0] / s, tv[1] / s, tv[2] / s, tv[3] / s);
        float4* iw = (float4*)(out + iOff + (size_t)row * 4);
        *iw = make_float4((float)ti[0], (float)ti[1], (float)ti[2], (float)ti[3]);
    }
}

extern "C" void kernel_launch(void* const* d_in, const int* in_sizes, int n_in,
                              void* d_out, int out_size, void* d_ws, size_t ws_size,
                              hipStream_t stream)
{
    const float* hs = (const float*)d_in[0];   // (T, 1536)
    const float* Wm = (const float*)d_in[1];   // (4, 1536)
    const float* We = (const float*)d_in[2];   // (16, 1536)
    float* out = (float*)d_out;
    const int T = in_sizes[0] / DD;            // 32768
    router_kernel<<<T / RPB, NTHR, 0, stream>>>(hs, Wm, We, out, T);
}